// Round 6
// baseline (242.587 us; speedup 1.0000x reference)
//
#include <hip/hip_runtime.h>
#include <hip/hip_bf16.h>

// Problem: B=8, S=4096, D=768
//   y = tanh(x @ W); scores = y . v; w = softmax_S(scores); out = sum_s w * x
constexpr int Bb = 8;
constexpr int Ss = 4096;
constexpr int Dd = 768;
constexpr int Mm = Bb * Ss;      // 32768 rows

typedef __bf16 bf16x8 __attribute__((ext_vector_type(8)));
typedef float f32x4 __attribute__((ext_vector_type(4)));

__device__ __forceinline__ float fast_tanh(float x) {
    return 1.f - 2.f / (__expf(2.f * x) + 1.f);
}

__device__ __forceinline__ void load_lds16(const void* g, void* l) {
    __builtin_amdgcn_global_load_lds(
        (const __attribute__((address_space(1))) unsigned int*)g,
        (__attribute__((address_space(3))) unsigned int*)l, 16, 0, 0);
}

// ---------------- Kernel 0: W[k][n] fp32 -> Wt[n][k] bf16, with the LDS
// bank-swizzle PRE-BAKED into the global layout (16B slot s -> s ^ ((n>>1)&3)
// within each 64B k-chunk). Proven: 0 bank conflicts on the B reads.
__global__ __launch_bounds__(256) void convW(const float* __restrict__ W,
                                             __bf16* __restrict__ Wt) {
    __shared__ float tile[32][33];
    const int tx = threadIdx.x & 31;
    const int ty = threadIdx.x >> 5;
    const int kb = blockIdx.x * 32;
    const int nb = blockIdx.y * 32;
#pragma unroll
    for (int i = 0; i < 32; i += 8)
        tile[ty + i][tx] = W[(size_t)(kb + ty + i) * Dd + nb + tx];
    __syncthreads();
#pragma unroll
    for (int i = 0; i < 32; i += 8) {
        const int n = nb + ty + i;
        const int txs = (tx & 7) | ((((tx >> 3) & 3) ^ ((n >> 1) & 3)) << 3);
        Wt[(size_t)n * Dd + kb + txs] = (__bf16)tile[tx][ty + i];
    }
}

// ---------------- Kernel 1: scores3[nb][m] = sum_n v[n]*tanh( (x@W)[m][n] )
// BM=128 x BN=256, n-split 3, 512 thr = 8 waves (2wm x 4wn), wave tile 64x64.
// FUSED fp32->bf16: A staged as FP32 via global_load_lds into a K-PANELED
// LDS layout (panel0 = k0..15, panel1 = k16..31; 64B rows; panel1 16B slot-
// pairs swapped AT THE SOURCE so readers never swap). Per-ds_read bank check:
// the 8 (row-parity x q&1 x panel/j) lane-groups map bijectively to the 8
// four-bank groups -> 8 accesses/bank = b128 floor, conflict-free. cvt
// fp32->bf16 in-register between ds_read and MFMA (hides under MFMA pipe).
// B: bf16 gl_lds from pre-swizzled Wt, 3-deep, 2-step flight (unchanged).
// LDS = 2x16(A) + 3x16(B) = 80 KB exact -> 2 blocks/CU; ssc overlays Bs.
// vmcnt ledger (in-order): prologue [A0,A0,B0,B0,B1,B1]; each step issues
// [A(k+1)x2, B(k+2)x2]; top-of-step vmcnt(2) retires A(k),B(k) and leaves
// B(k+1) flying; vmcnt(0) only at k=23. Eliminates the convX pass entirely.
__global__ __launch_bounds__(512, 4) void scores_gemm(
    const float* __restrict__ x, const __bf16* __restrict__ Wt,
    const float* __restrict__ v, float* __restrict__ scores3) {
    __shared__ float  As[2][4096];        // 2 x 16 KB fp32, k-paneled
    __shared__ __bf16 Bs[3][256 * 32];    // 3 x 16 KB

    const int t = threadIdx.x;
    // XCD swizzle: 768 blocks, 8 XCDs -> XCD x owns ids [x*96,(x+1)*96)
    const int id = blockIdx.x;
    const int ids = ((id & 7) * 96) + (id >> 3);
    const int mb = ids / 3;               // 0..255
    const int nb = ids - mb * 3;          // 0..2
    const int lane = t & 63;
    const int wave = t >> 6;
    const int wm = wave >> 2;             // 0..1 (64-row half)
    const int wn = wave & 3;              // 0..3 (64-col slice)
    const int quad = lane >> 4;
    const int lid = lane & 15;
    const int rslot = ((quad ^ ((lid >> 1) & 3)) * 8);   // B-read swizzle

    // ---- A staging (fp32, 2 shots of 512x16B):
    // shot0 -> panel0: dest f32 idx t*4; row=t>>2, slot=t&3; src k = slot*4
    // shot1 -> panel1: dest f32 idx 2048+t*4; src k = 16 + ((slot^1)*4)
    const int sarow = t >> 2;
    const float* axg0 = x + (size_t)(mb * 128 + sarow) * Dd + (t & 3) * 4;
    const float* axg1 = x + (size_t)(mb * 128 + sarow) * Dd + 16 + (((t & 3) ^ 1) * 4);

    // ---- B staging: 2 shots of 512x16B over the [256 x 64B] tile.
    const __bf16* bgp[2];
    int blp[2];
#pragma unroll
    for (int j = 0; j < 2; ++j) {
        const int flat = j * 8192 + t * 16;   // bytes
        const int col = flat >> 6;
        bgp[j] = Wt + (size_t)(nb * 256 + col) * Dd + ((flat & 63) >> 1);
        blp[j] = flat >> 1;                   // bf16 index into Bs[buf]
    }

    // ---- A-read constants: panel p_=quad>>1; 16B slots (q&1)*2+j, pair-
    // swapped for panel1 (storage already swapped -> XOR with p_).
    const int p_ = quad >> 1;
    const int sA0 = ((quad & 1) * 2 + 0) ^ p_;
    const int sA1 = ((quad & 1) * 2 + 1) ^ p_;
    const int abase = p_ * 2048 + sA0 * 4;    // f32 idx, + row*16
    const int abase1 = p_ * 2048 + sA1 * 4;

    f32x4 acc[4][4];
#pragma unroll
    for (int tm = 0; tm < 4; ++tm)
#pragma unroll
        for (int nt = 0; nt < 4; ++nt) acc[tm][nt] = (f32x4){0.f, 0.f, 0.f, 0.f};

    // ---- prologue: [A0,A0,B0,B0,B1,B1]
    load_lds16(axg0, &As[0][t * 4]);
    load_lds16(axg1, &As[0][2048 + t * 4]);
#pragma unroll
    for (int j = 0; j < 2; ++j) load_lds16(bgp[j], &Bs[0][blp[j]]);
#pragma unroll
    for (int j = 0; j < 2; ++j) load_lds16(bgp[j] + 32, &Bs[1][blp[j]]);

#pragma unroll
    for (int k = 0; k < 24; ++k) {
        // vmcnt(2): retire A(k),B(k); leave B(k+1)'s 2 loads in flight.
        if (k == 23) asm volatile("s_waitcnt vmcnt(0)" ::: "memory");
        else         asm volatile("s_waitcnt vmcnt(2)" ::: "memory");
        __builtin_amdgcn_sched_barrier(0);
        __builtin_amdgcn_s_barrier();     // publish buf k
        __builtin_amdgcn_sched_barrier(0);

        if (k < 23) {                     // A(k+1) fp32, 1-step flight
            load_lds16(axg0 + (k + 1) * 32, &As[(k + 1) & 1][t * 4]);
            load_lds16(axg1 + (k + 1) * 32, &As[(k + 1) & 1][2048 + t * 4]);
        }
        if (k < 22) {                     // B(k+2) bf16, 2-step flight
#pragma unroll
            for (int j = 0; j < 2; ++j)
                load_lds16(bgp[j] + (k + 2) * 32, &Bs[(k + 2) % 3][blp[j]]);
        }
        __builtin_amdgcn_sched_barrier(0);

        // ds_read A (fp32 paneled, conflict-free) + in-reg cvt; ds_read B.
        bf16x8 af[4], bfr[4];
#pragma unroll
        for (int tm = 0; tm < 4; ++tm) {
            const int row = wm * 64 + tm * 16 + lid;
            const f32x4 r1 = *(const f32x4*)(&As[k & 1][abase + row * 16]);
            const f32x4 r2 = *(const f32x4*)(&As[k & 1][abase1 + row * 16]);
            bf16x8 a;
            a[0] = (__bf16)r1[0]; a[1] = (__bf16)r1[1];
            a[2] = (__bf16)r1[2]; a[3] = (__bf16)r1[3];
            a[4] = (__bf16)r2[0]; a[5] = (__bf16)r2[1];
            a[6] = (__bf16)r2[2]; a[7] = (__bf16)r2[3];
            af[tm] = a;
        }
#pragma unroll
        for (int nt = 0; nt < 4; ++nt)
            bfr[nt] = *(const bf16x8*)(&Bs[k % 3][(wn * 64 + nt * 16 + lid) * 32 + rslot]);

        __builtin_amdgcn_s_setprio(1);
#pragma unroll
        for (int tm = 0; tm < 4; ++tm)
#pragma unroll
            for (int nt = 0; nt < 4; ++nt)
                acc[tm][nt] = __builtin_amdgcn_mfma_f32_16x16x32_bf16(af[tm], bfr[nt], acc[tm][nt], 0, 0, 0);
        __builtin_amdgcn_s_setprio(0);
    }

    // ---- epilogue: fold tanh*v over this block's 256 cols, reduce to rows.
    // ssc overlays Bs (all VMEM retired at k=23's vmcnt(0); barrier below).
    __syncthreads();
    float* ssc = (float*)&Bs[0][0];       // [8][64]

    float vv[4];
#pragma unroll
    for (int nt = 0; nt < 4; ++nt)
        vv[nt] = v[nb * 256 + wn * 64 + nt * 16 + lid];

#pragma unroll
    for (int tm = 0; tm < 4; ++tm)
#pragma unroll
        for (int r = 0; r < 4; ++r) {
            float s = 0.f;
#pragma unroll
            for (int nt = 0; nt < 4; ++nt) s += vv[nt] * fast_tanh(acc[tm][nt][r]);
            // C layout: col=lid, row=quad*4+r
            s += __shfl_xor(s, 1);
            s += __shfl_xor(s, 2);
            s += __shfl_xor(s, 4);
            s += __shfl_xor(s, 8);
            if (lid == 0) ssc[wave * 64 + tm * 16 + quad * 4 + r] = s;
        }
    __syncthreads();
    if (t < 128) {
        const int wmh = t >> 6;           // which 64-row half
        const int rl = t & 63;
        float s = 0.f;
#pragma unroll
        for (int ww = 0; ww < 4; ++ww) s += ssc[(wmh * 4 + ww) * 64 + rl];
        scores3[(size_t)nb * Mm + mb * 128 + t] = s;   // no atomics, no memset
    }
}

// ---------------- Kernel 2: softmax over S per batch row.
// Reads 3 n-split partials, writes UNNORMALIZED e to weights, 1/sum to sinv.
__global__ __launch_bounds__(256) void softmax_k(const float* __restrict__ scores3,
                                                 float* __restrict__ weights,
                                                 float* __restrict__ sinv) {
    const int b = blockIdx.x;
    const int t = threadIdx.x;
    const float* s0 = scores3 + (size_t)b * Ss;
    const float* s1 = s0 + Mm;
    const float* s2 = s1 + Mm;
    float* wgt = weights + (size_t)b * Ss;
    __shared__ float red[256];

    float mx = -1e30f;
    for (int i = t; i < Ss; i += 256) {
        const float sc = s0[i] + s1[i] + s2[i];
        wgt[i] = sc;
        mx = fmaxf(mx, sc);
    }
    red[t] = mx;
    __syncthreads();
    for (int o = 128; o > 0; o >>= 1) {
        if (t < o) red[t] = fmaxf(red[t], red[t + o]);
        __syncthreads();
    }
    mx = red[0];
    __syncthreads();
    float sum = 0.f;
    for (int i = t; i < Ss; i += 256) {
        const float e = __expf(wgt[i] - mx);
        wgt[i] = e;
        sum += e;
    }
    red[t] = sum;
    __syncthreads();
    for (int o = 128; o > 0; o >>= 1) {
        if (t < o) red[t] += red[t + o];
        __syncthreads();
    }
    if (t == 0) sinv[b] = 1.f / red[0];
}

// ---------------- Kernel 3a: per-chunk partial pool (no atomics)
// grid = (128 chunks, B) = 1024 blocks x 192 thr (4 blocks/CU, 12 waves/CU)
__global__ __launch_bounds__(192) void pool1(const float* __restrict__ x,
                                             const float* __restrict__ weights,
                                             float* __restrict__ partial) {
    const int b = blockIdx.y;
    const int c = blockIdx.x;            // 128 chunks x 32 rows
    const int t = threadIdx.x;           // owns float4 at d = t*4
    const float* base = x + ((size_t)b * Ss + c * 32) * Dd;
    const float* wrow = weights + (size_t)b * Ss + c * 32;
    float4 acc = make_float4(0.f, 0.f, 0.f, 0.f);
#pragma unroll 8
    for (int i = 0; i < 32; ++i) {
        const float ww = wrow[i];
        const float4 xv = *(const float4*)(base + (size_t)i * Dd + t * 4);
        acc.x += ww * xv.x;
        acc.y += ww * xv.y;
        acc.z += ww * xv.z;
        acc.w += ww * xv.w;
    }
    *(float4*)(partial + ((size_t)(b * 128 + c)) * Dd + t * 4) = acc;
}

// ---------------- Kernel 3b: out[b][d] = sinv[b] * sum_c partial[b][c][d]
// grid (6 d-segments, B) = 48 blocks x 128 thr: spreads the 3 MB reduction
// over 48 CUs (was 8 blocks = 8 CUs, ~10 us of single-CU BW; now ~3 us).
__global__ __launch_bounds__(128) void pool2(const float* __restrict__ partial,
                                             const float* __restrict__ sinv,
                                             float* __restrict__ out) {
    const int b = blockIdx.y;
    const int d = blockIdx.x * 128 + threadIdx.x;   // 0..767
    float s = 0.f;
#pragma unroll 8
    for (int c = 0; c < 128; ++c) s += partial[((size_t)(b * 128 + c)) * Dd + d];
    out[(size_t)b * Dd + d] = s * sinv[b];
}

extern "C" void kernel_launch(void* const* d_in, const int* in_sizes, int n_in,
                              void* d_out, int out_size, void* d_ws, size_t ws_size,
                              hipStream_t stream) {
    (void)in_sizes; (void)n_in; (void)ws_size; (void)out_size;
    const float* x = (const float*)d_in[0];
    const float* v = (const float*)d_in[1];
    const float* W = (const float*)d_in[2];

    char* ws = (char*)d_ws;
    // layout: Wt | scores3 | weights | sinv | partial   (~4.85 MB total)
    constexpr size_t OFF_WT = 0;
    constexpr size_t OFF_SC = 1179648;
    constexpr size_t OFF_WG = OFF_SC + 393216;
    constexpr size_t OFF_SI = OFF_WG + 131072;
    constexpr size_t OFF_PA = OFF_SI + 128;

    __bf16* Wt     = (__bf16*)(ws + OFF_WT);
    float* scores3 = (float*)(ws + OFF_SC);
    float* weights = (float*)(ws + OFF_WG);
    float* sinv    = (float*)(ws + OFF_SI);
    float* partial = (float*)(ws + OFF_PA);

    convW<<<dim3(Dd / 32, Dd / 32), 256, 0, stream>>>(W, Wt);
    scores_gemm<<<dim3(3 * Mm / 128), 512, 0, stream>>>(x, Wt, v, scores3);
    softmax_k<<<dim3(Bb), 256, 0, stream>>>(scores3, weights, sinv);
    pool1<<<dim3(128, Bb), 192, 0, stream>>>(x, weights, partial);
    pool2<<<dim3(6, Bb), 128, 0, stream>>>(partial, sinv, (float*)d_out);
}